// Round 14
// baseline (172.103 us; speedup 1.0000x reference)
//
#include <hip/hip_runtime.h>
#include <hip/hip_bf16.h>

// WindowAttention for MI355X (gfx950) — round 14.
// K1 qkv_gemm8: 256 thr = 4 waves, wave tile 64x128 (32 MFMA + 12 ds_reads
// per wave per k-step, was 16+8) — doubles per-wave MFMA work between
// barriers, halves barrier participants. Same 3-buffer rotation and barrier
// skeleton as replay-proven R10; vmcnt counts scaled exactly 2x (6 loads per
// STAGE per wave). prep_all = R10 gather version. K2 attn_proj3 unchanged.

typedef _Float16 f16;
typedef f16 f16x8 __attribute__((ext_vector_type(8)));
typedef f16 f16x4 __attribute__((ext_vector_type(4)));
typedef float f32x4 __attribute__((ext_vector_type(4)));

#define MFMA_F16(a, b, c) __builtin_amdgcn_mfma_f32_16x16x32_f16((a), (b), (c), 0, 0, 0)

#define AS_G __attribute__((address_space(1)))
#define AS_L __attribute__((address_space(3)))
#define GLOAD_LDS16(gp, lp) \
  __builtin_amdgcn_global_load_lds((const AS_G void*)(gp), (AS_L void*)(lp), 16, 0, 0)
#define WAITVM_(N) asm volatile("s_waitcnt vmcnt(" #N ")" ::: "memory")
#define WAITVM(N) WAITVM_(N)

namespace {
constexpr int kC = 384;
constexpr int kNTok = 4096;
constexpr float kScale = 0.17677669529663687f;  // 1/sqrt(32)
constexpr int kWqPackChunks = 72 * 12 * 64;     // 55296 x 16B
constexpr int kWpPackChunks = 24 * 12 * 64;     // 18432 x 16B
constexpr size_t kWqPackBytes = (size_t)kWqPackChunks * 16;  // 884736
constexpr size_t kWpPackBytes = (size_t)kWpPackChunks * 16;  // 294912
constexpr size_t kQkvWsBytes = (size_t)65536 * 1152 * 2;     // 150994944
constexpr size_t kWsNeed = kWqPackBytes + kWpPackBytes + kQkvWsBytes;
constexpr int kPrepXBlocks = 12288;                 // 4096*12*64 / 256
constexpr int kQkvPackChunksFb = 6 * 12 * 12 * 64;  // fallback layout
}

// ===================== split path =====================

// prep_all (R10 gather version): blocks [0,12288) pack x f32->f16 A-fragment
// order into xw; rest pack Wqkv/Wproj f16 in B-fragment order.
__global__ void prep_all(const float* __restrict__ x,
                         const float* __restrict__ Wqkv,
                         const float* __restrict__ Wproj,
                         f16* __restrict__ xw, f16* __restrict__ wq_pack,
                         f16* __restrict__ wp_pack) {
  int blk = blockIdx.x;
  if (blk < kPrepXBlocks) {
    int c = blk * 256 + threadIdx.x;  // < 4096*12*64
    int lane = c & 63;
    int t = c >> 6;
    int ks = t % 12;
    int mb = t / 12;
    int l15 = lane & 15, g = lane >> 4;
    int m = mb * 16 + l15;
    int b = m >> 12;
    int win = (m >> 6) & 63;
    int tok = m & 63;
    int n = ((win >> 3) * 8 + (tok >> 3)) * 64 + (win & 7) * 8 + (tok & 7);
    const float* src = x + ((size_t)(b << 12) + n) * kC + ks * 32 + g * 8;
    float4 v0 = *reinterpret_cast<const float4*>(src);
    float4 v1 = *reinterpret_cast<const float4*>(src + 4);
    f16x8 h = {(f16)v0.x, (f16)v0.y, (f16)v0.z, (f16)v0.w,
               (f16)v1.x, (f16)v1.y, (f16)v1.z, (f16)v1.w};
    *reinterpret_cast<f16x8*>(xw + (size_t)c * 8) = h;
    return;
  }
  int i = (blk - kPrepXBlocks) * 256 + threadIdx.x;
  if (i < kWqPackChunks) {
    int lane = i & 63;
    int chunk = i >> 6;
    int ks = chunk % 12;
    int t = chunk / 12;
    int l15 = lane & 15, g = lane >> 4;
    int n3 = t * 16 + l15;
    int k0 = ks * 32 + g * 8;
    f16x8 v;
    #pragma unroll
    for (int j = 0; j < 8; ++j)
      v[j] = (f16)Wqkv[(size_t)(k0 + j) * (3 * kC) + n3];
    *reinterpret_cast<f16x8*>(wq_pack + (size_t)i * 8) = v;
  } else if (i < kWqPackChunks + kWpPackChunks) {
    int p = i - kWqPackChunks;
    int lane = p & 63;
    int chunk = p >> 6;
    int ks = chunk % 12;
    int t = chunk / 12;
    int l15 = lane & 15, g = lane >> 4;
    int n = t * 16 + l15;
    int k0 = ks * 32 + g * 8;
    f16x8 v;
    #pragma unroll
    for (int j = 0; j < 8; ++j)
      v[j] = (f16)Wproj[(size_t)(k0 + j) * kC + n];
    *reinterpret_cast<f16x8*>(wp_pack + (size_t)p * 8) = v;
  }
}

// K1: qkv = xw @ Wqkv + b. 256x128 tile, 3-buffer counted-vmcnt pipeline.
// 256 thr = 4 waves, each wave owns 64 rows (its window) x all 128 cols:
// acc[4][8], 32 MFMA + 12 ds_reads per k-step. STAGE: 6 gload_lds per wave
// (A chunks wid,wid+4,wid+8,wid+12; B chunks wid,wid+4). vmcnt = R10 x2.
// Output packed [b*64+win][h*3+sec][...2048]: q,k [tok][d]; v [d][tok].
__global__ __launch_bounds__(256, 2) void qkv_gemm8(
    const f16* __restrict__ xw, const float* __restrict__ b_qkv,
    const f16* __restrict__ wq_pack, f16* __restrict__ qkv_ws) {
  // 3 bufs x (A 16KB + B 8KB) = 72 KB; epilogue reuses first 64 KB.
  __shared__ alignas(1024) char smem[73728];

  const int tid = threadIdx.x;
  const int wid = tid >> 6;  // 0..3 (= window / 64-row group)
  const int lane = tid & 63;
  const int g = lane >> 4;
  const int l15 = lane & 15;

  // XCD swizzle: 2304 = 8*288; n-major within XCD -> A-panel L2 reuse.
  int bid = blockIdx.x;
  int wg = (bid & 7) * 288 + (bid >> 3);
  int m_grp = wg / 9;  // [0,256): 256-row panel = 4 windows
  int n_grp = wg - m_grp * 9;
  const int mb0 = m_grp * 16;  // 16-row frag chunks
  const int nb0 = n_grp * 8;

  // STAGE: 6 x global_load_lds(16B) per wave (A x4, B x2)
  #define STAGE(KS, BUF)                                                       \
    do {                                                                       \
      char* la = smem + (BUF) * 24576;                                         \
      char* lb = la + 16384;                                                   \
      _Pragma("unroll") for (int q = 0; q < 4; ++q) {                          \
        const f16* ga =                                                        \
            xw + (((size_t)(mb0 + wid + q * 4) * 12 + (KS)) * 64 + lane) * 8;  \
        GLOAD_LDS16(ga, la + (wid + q * 4) * 1024);                            \
      }                                                                        \
      _Pragma("unroll") for (int q = 0; q < 2; ++q) {                          \
        const f16* gb = wq_pack +                                              \
            (((size_t)(nb0 + wid + q * 4) * 12 + (KS)) * 64 + lane) * 8;       \
        GLOAD_LDS16(gb, lb + (wid + q * 4) * 1024);                            \
      }                                                                        \
    } while (0)

  f32x4 acc[4][8];
  #pragma unroll
  for (int mt = 0; mt < 4; ++mt)
    #pragma unroll
    for (int nt = 0; nt < 8; ++nt) acc[mt][nt] = {0.f, 0.f, 0.f, 0.f};

  STAGE(0, 0);
  STAGE(1, 1);
  STAGE(2, 2);
  WAITVM(12);  // stage0 done (2 stages x 6 loads outstanding)
  __builtin_amdgcn_sched_barrier(0);
  __builtin_amdgcn_s_barrier();

  #define KITER(T, ENDVM)                                                      \
    do {                                                                       \
      constexpr int buf = (T) % 3;                                             \
      f16x8 af[4], bf[8];                                                      \
      _Pragma("unroll") for (int mt = 0; mt < 4; ++mt) af[mt] =                \
          *reinterpret_cast<const f16x8*>(smem + buf * 24576 +                 \
                                          (wid * 4 + mt) * 1024 + lane * 16);  \
      _Pragma("unroll") for (int nt = 0; nt < 8; ++nt) bf[nt] =                \
          *reinterpret_cast<const f16x8*>(smem + buf * 24576 + 16384 +         \
                                          nt * 1024 + lane * 16);              \
      asm volatile("s_waitcnt lgkmcnt(0)" ::: "memory");                       \
      __builtin_amdgcn_sched_barrier(0);                                       \
      __builtin_amdgcn_s_barrier();                                            \
      if ((T) < 9) {                                                           \
        STAGE((T) + 3, buf);                                                   \
      }                                                                        \
      __builtin_amdgcn_s_setprio(1);                                           \
      _Pragma("unroll") for (int mt = 0; mt < 4; ++mt)                         \
          _Pragma("unroll") for (int nt = 0; nt < 8; ++nt) acc[mt][nt] =       \
          MFMA_F16(af[mt], bf[nt], acc[mt][nt]);                               \
      __builtin_amdgcn_s_setprio(0);                                           \
      WAITVM(ENDVM);                                                           \
      __builtin_amdgcn_sched_barrier(0);                                       \
      __builtin_amdgcn_s_barrier();                                            \
    } while (0)

  KITER(0, 12);
  KITER(1, 12);
  KITER(2, 12);
  KITER(3, 12);
  KITER(4, 12);
  KITER(5, 12);
  KITER(6, 12);
  KITER(7, 12);
  KITER(8, 12);
  KITER(9, 6);
  KITER(10, 0);
  KITER(11, 0);
  #undef KITER
  #undef STAGE

  // ---- epilogue: bias, LDS re-order (v transposed+swizzled), stores ----
  // eo: [win_loc(4)][hsec_loc(4)][2048] = 64 KB; wave wid owns win_loc=wid.
  f16* eo = (f16*)smem;
  #pragma unroll
  for (int nt = 0; nt < 8; ++nt) {
    int col128 = nt * 16 + l15;
    float bias = b_qkv[n_grp * 128 + col128];
    int hsec_loc = nt >> 1;  // wave-uniform
    int d = col128 & 31;
    int sec = (n_grp * 4 + hsec_loc) / 12;
    int base = (wid * 4 + hsec_loc) * 2048;
    #pragma unroll
    for (int mt = 0; mt < 4; ++mt) {
      #pragma unroll
      for (int j = 0; j < 4; ++j) {
        int tok = mt * 16 + g * 4 + j;
        f16 hv = (f16)(acc[mt][nt][j] + bias);
        if (sec == 2)
          eo[base + d * 64 + (tok ^ ((d & 7) << 3))] = hv;  // [d][tok] swz
        else
          eo[base + tok * 32 + d] = hv;                      // [tok][d]
      }
    }
  }
  __syncthreads();
  // copy out: 4096 x 16B units over 256 threads
  #pragma unroll
  for (int i = 0; i < 16; ++i) {
    int u = tid + i * 256;
    int win_loc = u >> 10;       // 0..3
    int cbl = (u >> 8) & 3;
    int inner = u & 255;
    int cb = n_grp * 4 + cbl;
    int h = cb % 12;
    int sec = cb / 12;
    size_t dst = ((size_t)(m_grp * 4 + win_loc) * 36 + h * 3 + sec) * 2048 +
                 (size_t)inner * 8;
    f16x8 hv;
    if (sec == 2) {
      int d = inner >> 3;
      int t0 = inner & 7;
      hv = *reinterpret_cast<const f16x8*>(eo + (win_loc * 4 + cbl) * 2048 +
                                           d * 64 + ((t0 * 8) ^ ((d & 7) << 3)));
    } else {
      hv = *reinterpret_cast<const f16x8*>(eo + (size_t)u * 8);
    }
    *reinterpret_cast<f16x8*>(qkv_ws + dst) = hv;
  }
}

// ---- K2 helpers (unchanged, proven in R7/R8/R10/R12/R13) ----
__device__ __forceinline__ void load_qkv(const f16* __restrict__ hb,
                                         f16x8 (&qf)[4], f16x8 (&kf)[4],
                                         f16x8 (&vf)[2][2], int g, int l15) {
  #pragma unroll
  for (int mt = 0; mt < 4; ++mt)
    qf[mt] = *reinterpret_cast<const f16x8*>(hb + (mt * 16 + l15) * 32 + g * 8);
  #pragma unroll
  for (int nt = 0; nt < 4; ++nt)
    kf[nt] = *reinterpret_cast<const f16x8*>(hb + 2048 + (nt * 16 + l15) * 32 +
                                             g * 8);
  #pragma unroll
  for (int nd = 0; nd < 2; ++nd)
    #pragma unroll
    for (int ks = 0; ks < 2; ++ks)
      vf[nd][ks] = *reinterpret_cast<const f16x8*>(
          hb + 4096 + (nd * 16 + l15) * 64 + ks * 32 + g * 8);
}

__device__ __forceinline__ void attn_one(const f16x8 (&qf)[4],
                                         const f16x8 (&kf)[4],
                                         const f16x8 (&vf)[2][2],
                                         f16 (&ao)[64][392], f16 (&ps)[16][68],
                                         int wid, int g, int l15) {
  const f32x4 zero4 = {0.f, 0.f, 0.f, 0.f};
  #pragma unroll
  for (int mt = 0; mt < 4; ++mt) {
    f32x4 sw0 = MFMA_F16(kf[0], qf[mt], zero4);
    f32x4 sw1 = MFMA_F16(kf[1], qf[mt], zero4);
    f32x4 sw2 = MFMA_F16(kf[2], qf[mt], zero4);
    f32x4 sw3 = MFMA_F16(kf[3], qf[mt], zero4);
    float p[16];
    #pragma unroll
    for (int j = 0; j < 4; ++j) {
      p[j] = sw0[j] * kScale;
      p[4 + j] = sw1[j] * kScale;
      p[8 + j] = sw2[j] * kScale;
      p[12 + j] = sw3[j] * kScale;
    }
    float m0 = fmaxf(fmaxf(p[0], p[1]), fmaxf(p[2], p[3]));
    float m1 = fmaxf(fmaxf(p[4], p[5]), fmaxf(p[6], p[7]));
    float m2 = fmaxf(fmaxf(p[8], p[9]), fmaxf(p[10], p[11]));
    float m3 = fmaxf(fmaxf(p[12], p[13]), fmaxf(p[14], p[15]));
    float mx = fmaxf(fmaxf(m0, m1), fmaxf(m2, m3));
    mx = fmaxf(mx, __shfl_xor(mx, 16));
    mx = fmaxf(mx, __shfl_xor(mx, 32));
    #pragma unroll
    for (int i = 0; i < 16; ++i) p[i] = __expf(p[i] - mx);
    float s01 = (p[0] + p[1]) + (p[2] + p[3]);
    float s23 = (p[4] + p[5]) + (p[6] + p[7]);
    float s45 = (p[8] + p[9]) + (p[10] + p[11]);
    float s67 = (p[12] + p[13]) + (p[14] + p[15]);
    float s = (s01 + s23) + (s45 + s67);
    s += __shfl_xor(s, 16);
    s += __shfl_xor(s, 32);
    float inv = __builtin_amdgcn_rcpf(s);
    #pragma unroll
    for (int nt = 0; nt < 4; ++nt) {
      f16x4 h = {(f16)(p[nt * 4] * inv), (f16)(p[nt * 4 + 1] * inv),
                 (f16)(p[nt * 4 + 2] * inv), (f16)(p[nt * 4 + 3] * inv)};
      *reinterpret_cast<f16x4*>(&ps[l15][nt * 16 + g * 4]) = h;
    }
    f32x4 o0 = zero4, o1 = zero4;
    #pragma unroll
    for (int ks = 0; ks < 2; ++ks) {
      f16x8 pa = *reinterpret_cast<const f16x8*>(&ps[l15][ks * 32 + g * 8]);
      o0 = MFMA_F16(pa, vf[0][ks], o0);
      o1 = MFMA_F16(pa, vf[1][ks], o1);
    }
    #pragma unroll
    for (int j = 0; j < 4; ++j) {
      ao[mt * 16 + g * 4 + j][wid * 32 + l15] = (f16)o0[j];
      ao[mt * 16 + g * 4 + j][wid * 32 + 16 + l15] = (f16)o1[j];
    }
  }
}

__device__ __forceinline__ void proj_store(const f16 (&ao)[64][392],
                                           const f16* __restrict__ wp_pack,
                                           float* __restrict__ out, int b,
                                           int win, int wid, int g, int l15,
                                           int lane) {
  const f32x4 zero4 = {0.f, 0.f, 0.f, 0.f};
  const int wh = win >> 3, ww = win & 7;
  f32x4 pacc[4][2];
  #pragma unroll
  for (int mt = 0; mt < 4; ++mt) {
    pacc[mt][0] = zero4;
    pacc[mt][1] = zero4;
  }
  const f16* pp0 = wp_pack + ((size_t)((wid * 2) * 12) * 64 + lane) * 8;
  const f16* pp1 = wp_pack + ((size_t)((wid * 2 + 1) * 12) * 64 + lane) * 8;
  f16x8 pb0[2], pb1[2];
  pb0[0] = *reinterpret_cast<const f16x8*>(pp0);
  pb1[0] = *reinterpret_cast<const f16x8*>(pp1);
  #pragma unroll
  for (int ks = 0; ks < 12; ++ks) {
    const int cur = ks & 1;
    if (ks < 11) {
      pb0[cur ^ 1] = *reinterpret_cast<const f16x8*>(pp0 + (ks + 1) * 512);
      pb1[cur ^ 1] = *reinterpret_cast<const f16x8*>(pp1 + (ks + 1) * 512);
    }
    f16x8 paf[4];
    #pragma unroll
    for (int mt = 0; mt < 4; ++mt)
      paf[mt] = *reinterpret_cast<const f16x8*>(
          &ao[mt * 16 + l15][ks * 32 + g * 8]);
    #pragma unroll
    for (int mt = 0; mt < 4; ++mt) {
      pacc[mt][0] = MFMA_F16(paf[mt], pb0[cur], pacc[mt][0]);
      pacc[mt][1] = MFMA_F16(paf[mt], pb1[cur], pacc[mt][1]);
    }
  }
  const size_t outbase = (size_t)b * kNTok * kC;
  #pragma unroll
  for (int mt = 0; mt < 4; ++mt) {
    #pragma unroll
    for (int j = 0; j < 4; ++j) {
      int rr = mt * 16 + g * 4 + j;
      int n = (wh * 8 + (rr >> 3)) * 64 + ww * 8 + (rr & 7);
      float* orow = out + outbase + (size_t)n * kC + wid * 32;
      orow[l15] = pacc[mt][0][j];
      orow[16 + l15] = pacc[mt][1][j];
    }
  }
}

// K2: 12 waves = 12 heads; 2 windows per block with register prefetch.
__global__ __launch_bounds__(768, 3) void attn_proj3(
    const f16* __restrict__ qkv_ws, const f16* __restrict__ wp_pack,
    float* __restrict__ out) {
  __shared__ alignas(16) f16 ao[64][392];
  __shared__ alignas(16) f16 p_s[12][16][68];

  const int tid = threadIdx.x;
  const int wid = tid >> 6;  // head
  const int lane = tid & 63;
  const int g = lane >> 4;
  const int l15 = lane & 15;

  int bid = (int)blockIdx.x;             // 512 blocks
  int w2 = (bid & 7) * 64 + (bid >> 3);  // XCD swizzle
  const int b = w2 >> 5;
  const int win0 = (w2 & 31) * 2;
  const int win1 = win0 + 1;

  const f16* hb0 = qkv_ws + ((size_t)(b * 64 + win0) * 36 + wid * 3) * 2048;
  const f16* hb1 = hb0 + 36 * 2048;

  f16x8 qA[4], kA[4], vA[2][2], qB[4], kB[4], vB[2][2];
  load_qkv(hb0, qA, kA, vA, g, l15);
  __builtin_amdgcn_sched_barrier(0);
  attn_one(qA, kA, vA, ao, p_s[wid], wid, g, l15);
  load_qkv(hb1, qB, kB, vB, g, l15);  // prefetch window 1 during proj 0
  __builtin_amdgcn_sched_barrier(0);
  __syncthreads();
  proj_store(ao, wp_pack, out, b, win0, wid, g, l15, lane);
  __syncthreads();  // proj0 done reading ao before window-1 PV overwrites
  attn_one(qB, kB, vB, ao, p_s[wid], wid, g, l15);
  __syncthreads();
  proj_store(ao, wp_pack, out, b, win1, wid, g, l15, lane);
}

// ===================== fallback path (round-3 fused kernel) =====================

__global__ void prep_weights_fb(const float* __restrict__ Wqkv,
                                const float* __restrict__ Wproj,
                                f16* __restrict__ wq_pack,
                                f16* __restrict__ wp_pack) {
  int i = blockIdx.x * 256 + threadIdx.x;
  if (i < kQkvPackChunksFb) {
    int lane = i & 63;
    int chunk = i >> 6;
    int ks = chunk % 12;
    int t = (chunk / 12) % 12;
    int hp = chunk / 144;
    int l15 = lane & 15, g = lane >> 4;
    int base = t * 16;
    int hh = base / 96;
    int cc = base - hh * 96;
    int sec = cc >> 5;
    int dbhi = cc & 31;
    int n3 = sec * kC + (2 * hp + hh) * 32 + dbhi + l15;
    int k0 = ks * 32 + g * 8;
    f16x8 v;
    #pragma unroll
    for (int j = 0; j < 8; ++j)
      v[j] = (f16)Wqkv[(size_t)(k0 + j) * (3 * kC) + n3];
    *reinterpret_cast<f16x8*>(wq_pack + (size_t)i * 8) = v;
  } else if (i < kQkvPackChunksFb + kWpPackChunks) {
    int p = i - kQkvPackChunksFb;
    int lane = p & 63;
    int chunk = p >> 6;
    int ks = chunk % 12;
    int t = chunk / 12;
    int l15 = lane & 15, g = lane >> 4;
    int n = t * 16 + l15;
    int k0 = ks * 32 + g * 8;
    f16x8 v;
    #pragma unroll
    for (int j = 0; j < 8; ++j)
      v[j] = (f16)Wproj[(size_t)(k0 + j) * kC + n];
    *reinterpret_cast<f16x8*>(wp_pack + (size_t)p * 8) = v;
  }
}

__global__ __launch_bounds__(512, 2) void win_attn_fused_fb(
    const float* __restrict__ x, const float* __restrict__ b_qkv,
    const f16* __restrict__ wq_pack, const f16* __restrict__ wp_pack,
    float* __restrict__ out) {
  __shared__ alignas(16) f16 xs[64][392];
  __shared__ alignas(16) f16 ao[64][392];
  __shared__ alignas(16) f16 q_s[2][64][40];
  __shared__ alignas(16) f16 k_s[2][64][40];
  __shared__ alignas(16) f16 vT[2][32][72];
  __shared__ alignas(16) f16 p_s[8][16][72];

  const int tid = threadIdx.x;
  const int wid = tid >> 6;
  const int lane = tid & 63;
  const int g = lane >> 4;
  const int l15 = lane & 15;
  const int wm = wid >> 2;
  const int wn = wid & 3;

  const int blk = blockIdx.x;
  const int b = blk >> 6;
  const int win = blk & 63;
  const int wh = win >> 3;
  const int ww = win & 7;

  const f32x4 zero4 = {0.f, 0.f, 0.f, 0.f};

  {
    const float* xb = x + (size_t)b * kNTok * kC;
    #pragma unroll
    for (int it = 0; it < 12; ++it) {
      int idx = tid + it * 512;
      int r = idx / 96;
      int c4 = idx - r * 96;
      int n = (wh * 8 + (r >> 3)) * 64 + ww * 8 + (r & 7);
      float4 v = *reinterpret_cast<const float4*>(xb + (size_t)n * kC + c4 * 4);
      f16x4 hv = {(f16)v.x, (f16)v.y, (f16)v.z, (f16)v.w};
      *reinterpret_cast<f16x4*>(&xs[r][c4 * 4]) = hv;
    }
  }
  __syncthreads();

  for (int hp = 0; hp < 6; ++hp) {
    f32x4 acc[2][3];
    #pragma unroll
    for (int mt = 0; mt < 2; ++mt)
      #pragma unroll
      for (int nt = 0; nt < 3; ++nt) acc[mt][nt] = zero4;

    const f16* bptr[3];
    int secv[3], dbv[3], hhv[3];
    #pragma unroll
    for (int nt = 0; nt < 3; ++nt) {
      int t = wn * 3 + nt;
      int base = t * 16;
      int hh = base / 96;
      int cc = base - hh * 96;
      hhv[nt] = hh;
      secv[nt] = cc >> 5;
      dbv[nt] = cc & 31;
      bptr[nt] = wq_pack + ((size_t)((hp * 12 + t) * 12) * 64 + lane) * 8;
    }

    f16x8 bf[4][3];
    f16x8 af[2][2];
    #pragma unroll
    for (int p = 0; p < 3; ++p)
      #pragma unroll
      for (int nt = 0; nt < 3; ++nt)
        bf[p][nt] = *reinterpret_cast<const f16x8*>(bptr[nt] + p * 512);
    #pragma unroll
    for (int mt = 0; mt < 2; ++mt)
      af[0][mt] = *reinterpret_cast<const f16x8*>(
          &xs[wm * 32 + mt * 16 + l15][g * 8]);

    #pragma unroll
    for (int ks = 0; ks < 12; ++ks) {
      const int cur = ks & 3;
      const int ca = ks & 1;
      if (ks < 9) {
        const int nx = (ks + 3) & 3;
        #pragma unroll
        for (int nt = 0; nt < 3; ++nt)
          bf[nx][nt] =
              *reinterpret_cast<const f16x8*>(bptr[nt] + (ks + 3) * 512);
      }
      if (ks < 11) {
        #pragma unroll
        for (int mt = 0; mt < 2; ++mt)
          af[ca ^ 1][mt] = *reinterpret_cast<const f16x8*>(
              &xs[wm * 32 + mt * 16 + l15][(ks + 1) * 32 + g * 8]);
      }
      #pragma unroll
      for (int mt = 0; mt < 2; ++mt)
        #pragma unroll
        for (int nt = 0; nt < 3; ++nt)
          acc[mt][nt] = MFMA_F16(af[ca][mt], bf[cur][nt], acc[mt][nt]);
    }

    #pragma unroll
    for (int nt = 0; nt < 3; ++nt) {
      int hh = hhv[nt], sec = secv[nt];
      int col = dbv[nt] + l15;
      float bias = b_qkv[sec * kC + (2 * hp + hh) * 32 + col];
      #pragma unroll
      for (int mt = 0; mt < 2; ++mt) {
        #pragma unroll
        for (int j = 0; j < 4; ++j) {
          int r = wm * 32 + mt * 16 + g * 4 + j;
          f16 hv = (f16)(acc[mt][nt][j] + bias);
          if (sec == 0) q_s[hh][r][col] = hv;
          else if (sec == 1) k_s[hh][r][col] = hv;
          else vT[hh][col][r] = hv;
        }
      }
    }
    __syncthreads();

    f32x4 sacc[4];
    #pragma unroll
    for (int nt = 0; nt < 4; ++nt) sacc[nt] = zero4;
    f16x8 qa = *reinterpret_cast<const f16x8*>(&q_s[wm][wn * 16 + l15][g * 8]);
    #pragma unroll
    for (int nt = 0; nt < 4; ++nt) {
      f16x8 kb =
          *reinterpret_cast<const f16x8*>(&k_s[wm][nt * 16 + l15][g * 8]);
      sacc[nt] = MFMA_F16(qa, kb, sacc[nt]);
    }

    float pv[4][4];
    #pragma unroll
    for (int j = 0; j < 4; ++j) {
      float m = -1e30f;
      #pragma unroll
      for (int nt = 0; nt < 4; ++nt) {
        pv[nt][j] = sacc[nt][j] * kScale;
        m = fmaxf(m, pv[nt][j]);
      }
      m = fmaxf(m, __shfl_xor(m, 1));
      m = fmaxf(m, __shfl_xor(m, 2));
      m = fmaxf(m, __shfl_xor(m, 4));
      m = fmaxf(m, __shfl_xor(m, 8));
      float s = 0.f;
      #pragma unroll
      for (int nt = 0; nt < 4; ++nt) {
        pv[nt][j] = __expf(pv[nt][j] - m);
        s += pv[nt][j];
      }
      s += __shfl_xor(s, 1);
      s += __shfl_xor(s, 2);
      s += __shfl_xor(s, 4);
      s += __shfl_xor(s, 8);
      float inv = 1.0f / s;
      #pragma unroll
      for (int nt = 0; nt < 4; ++nt)
        p_s[wid][g * 4 + j][nt * 16 + l15] = (f16)(pv[nt][j] * inv);
    }

    f32x4 oacc[2];
    oacc[0] = zero4;
    oacc[1] = zero4;
    #pragma unroll
    for (int ks = 0; ks < 2; ++ks) {
      f16x8 pa =
          *reinterpret_cast<const f16x8*>(&p_s[wid][l15][ks * 32 + g * 8]);
      #pragma unroll
      for (int nt = 0; nt < 2; ++nt) {
        f16x8 vb = *reinterpret_cast<const f16x8*>(
            &vT[wm][nt * 16 + l15][ks * 32 + g * 8]);
        oacc[nt] = MFMA_F16(pa, vb, oacc[nt]);
      }
    }
    #pragma unroll
    for (int nt = 0; nt < 2; ++nt)
      #pragma unroll
      for (int j = 0; j < 4; ++j)
        ao[wn * 16 + g * 4 + j][(2 * hp + wm) * 32 + nt * 16 + l15] =
            (f16)oacc[nt][j];
    __syncthreads();
  }

  f32x4 pacc[2][6];
  #pragma unroll
  for (int mt = 0; mt < 2; ++mt)
    #pragma unroll
    for (int nt = 0; nt < 6; ++nt) pacc[mt][nt] = zero4;

  const f16* pptr[6];
  #pragma unroll
  for (int nt = 0; nt < 6; ++nt) {
    int t = wn * 6 + nt;
    pptr[nt] = wp_pack + ((size_t)(t * 12) * 64 + lane) * 8;
  }
  f16x8 pbf[3][6];
  f16x8 paf[2][2];
  #pragma unroll
  for (int p = 0; p < 2; ++p)
    #pragma unroll
    for (int nt = 0; nt < 6; ++nt)
      pbf[p][nt] = *reinterpret_cast<const f16x8*>(pptr[nt] + p * 512);
  #pragma unroll
  for (int mt = 0; mt < 2; ++mt)
    paf[0][mt] =
        *reinterpret_cast<const f16x8*>(&ao[wm * 32 + mt * 16 + l15][g * 8]);

  #pragma unroll
  for (int ks = 0; ks < 12; ++ks) {
    const int cur = ks % 3;
    const int ca = ks & 1;
    if (ks < 10) {
      const int nx = (ks + 2) % 3;
      #pragma unroll
      for (int nt = 0; nt < 6; ++nt)
        pbf[nx][nt] =
            *reinterpret_cast<const f16x8*>(pptr[nt] + (ks + 2) * 512);
    }
    if (ks < 11) {
      #pragma unroll
      for (int mt = 0; mt < 2; ++mt)
        paf[ca ^ 1][mt] = *reinterpret_cast<const f16x8*>(
            &ao[wm * 32 + mt * 16 + l15][(ks + 1) * 32 + g * 8]);
    }
    #pragma unroll
    for (int mt = 0; mt < 2; ++mt)
      #pragma unroll
      for (int nt = 0; nt < 6; ++nt)
        pacc[mt][nt] = MFMA_F16(paf[ca][mt], pbf[cur][nt], pacc[mt][nt]);
  }

  const size_t outbase = (size_t)b * kNTok * kC;
  #pragma unroll
  for (int mt = 0; mt < 2; ++mt) {
    #pragma unroll
    for (int j = 0; j < 4; ++j) {
      int r = wm * 32 + mt * 16 + g * 4 + j;
      int n = (wh * 8 + (r >> 3)) * 64 + ww * 8 + (r & 7);
      float* orow = out + outbase + (size_t)n * kC + wn * 96;
      #pragma unroll
      for (int nt = 0; nt < 6; ++nt) orow[nt * 16 + l15] = pacc[mt][nt][j];
    }
  }
}

// ===================== launch =====================

extern "C" void kernel_launch(void* const* d_in, const int* in_sizes, int n_in,
                              void* d_out, int out_size, void* d_ws,
                              size_t ws_size, hipStream_t stream) {
  const float* x = (const float*)d_in[0];
  const float* Wqkv = (const float*)d_in[1];
  const float* bqkv = (const float*)d_in[2];
  const float* Wproj = (const float*)d_in[3];
  float* out = (float*)d_out;

  if (ws_size >= kWsNeed) {
    f16* wq_pack = (f16*)d_ws;
    f16* wp_pack = (f16*)((char*)d_ws + kWqPackBytes);
    f16* qkv_ws = (f16*)((char*)d_ws + kWqPackBytes + kWpPackBytes);
    f16* xw = (f16*)d_out;  // 50 MB scratch inside the 100 MB output buffer

    int prep_blocks =
        kPrepXBlocks + (kWqPackChunks + kWpPackChunks + 255) / 256;  // 12576
    hipLaunchKernelGGL(prep_all, dim3(prep_blocks), dim3(256), 0, stream, x,
                       Wqkv, Wproj, xw, wq_pack, wp_pack);
    hipLaunchKernelGGL(qkv_gemm8, dim3(2304), dim3(256), 0, stream, xw, bqkv,
                       wq_pack, qkv_ws);
    hipLaunchKernelGGL(attn_proj3, dim3(512), dim3(768), 0, stream, qkv_ws,
                       wp_pack, out);
  } else {
    f16* wq_pack = (f16*)d_ws;
    f16* wp_pack = (f16*)((char*)d_ws + (size_t)kQkvPackChunksFb * 16);
    int prep_threads = kQkvPackChunksFb + kWpPackChunks;
    hipLaunchKernelGGL(prep_weights_fb, dim3((prep_threads + 255) / 256),
                       dim3(256), 0, stream, Wqkv, Wproj, wq_pack, wp_pack);
    hipLaunchKernelGGL(win_attn_fused_fb, dim3(16 * 64), dim3(512), 0, stream,
                       x, bqkv, wq_pack, wp_pack, out);
  }
}

// Round 15
// 160.676 us; speedup vs baseline: 1.0711x; 1.0711x over previous
//
#include <hip/hip_runtime.h>
#include <hip/hip_bf16.h>

// WindowAttention for MI355X (gfx950) — round 15: lock in proven best (R10).
// R14's 4-wave/64x128 K1 regressed (4x redundant LDS-B reads, fewer resident
// waves). Ledger of the 2-barrier K1 class: 128^2/8w=78.6, 256x128/8w=74.0
// (best), 256x128/4w=88.8, 2-buf=race, MFMA-reorder=neutral, barrier-free=128,
// A-reg-staged=162 -> 74us (~790 TF) is this structure's ceiling (matches the
// documented ~800-900 TF class limit). K2 ~45us (~86% BW), prep ~28us (~floor).
// This round: exact R10 composition, byte-for-byte.

typedef _Float16 f16;
typedef f16 f16x8 __attribute__((ext_vector_type(8)));
typedef f16 f16x4 __attribute__((ext_vector_type(4)));
typedef float f32x4 __attribute__((ext_vector_type(4)));

#define MFMA_F16(a, b, c) __builtin_amdgcn_mfma_f32_16x16x32_f16((a), (b), (c), 0, 0, 0)

#define AS_G __attribute__((address_space(1)))
#define AS_L __attribute__((address_space(3)))
#define GLOAD_LDS16(gp, lp) \
  __builtin_amdgcn_global_load_lds((const AS_G void*)(gp), (AS_L void*)(lp), 16, 0, 0)
#define WAITVM_(N) asm volatile("s_waitcnt vmcnt(" #N ")" ::: "memory")
#define WAITVM(N) WAITVM_(N)

namespace {
constexpr int kC = 384;
constexpr int kNTok = 4096;
constexpr float kScale = 0.17677669529663687f;  // 1/sqrt(32)
constexpr int kWqPackChunks = 72 * 12 * 64;     // 55296 x 16B
constexpr int kWpPackChunks = 24 * 12 * 64;     // 18432 x 16B
constexpr size_t kWqPackBytes = (size_t)kWqPackChunks * 16;  // 884736
constexpr size_t kWpPackBytes = (size_t)kWpPackChunks * 16;  // 294912
constexpr size_t kQkvWsBytes = (size_t)65536 * 1152 * 2;     // 150994944
constexpr size_t kWsNeed = kWqPackBytes + kWpPackBytes + kQkvWsBytes;
constexpr int kPrepXBlocks = 12288;                 // 4096*12*64 / 256
constexpr int kQkvPackChunksFb = 6 * 12 * 12 * 64;  // fallback layout
}

// ===================== split path =====================

// prep_all: blocks [0,12288) pack x f32->f16 A-fragment order into xw;
// rest pack Wqkv/Wproj f16 in B-fragment order.
__global__ void prep_all(const float* __restrict__ x,
                         const float* __restrict__ Wqkv,
                         const float* __restrict__ Wproj,
                         f16* __restrict__ xw, f16* __restrict__ wq_pack,
                         f16* __restrict__ wp_pack) {
  int blk = blockIdx.x;
  if (blk < kPrepXBlocks) {
    int c = blk * 256 + threadIdx.x;  // < 4096*12*64
    int lane = c & 63;
    int t = c >> 6;
    int ks = t % 12;
    int mb = t / 12;
    int l15 = lane & 15, g = lane >> 4;
    int m = mb * 16 + l15;
    int b = m >> 12;
    int win = (m >> 6) & 63;
    int tok = m & 63;
    int n = ((win >> 3) * 8 + (tok >> 3)) * 64 + (win & 7) * 8 + (tok & 7);
    const float* src = x + ((size_t)(b << 12) + n) * kC + ks * 32 + g * 8;
    float4 v0 = *reinterpret_cast<const float4*>(src);
    float4 v1 = *reinterpret_cast<const float4*>(src + 4);
    f16x8 h = {(f16)v0.x, (f16)v0.y, (f16)v0.z, (f16)v0.w,
               (f16)v1.x, (f16)v1.y, (f16)v1.z, (f16)v1.w};
    *reinterpret_cast<f16x8*>(xw + (size_t)c * 8) = h;
    return;
  }
  int i = (blk - kPrepXBlocks) * 256 + threadIdx.x;
  if (i < kWqPackChunks) {
    int lane = i & 63;
    int chunk = i >> 6;
    int ks = chunk % 12;
    int t = chunk / 12;
    int l15 = lane & 15, g = lane >> 4;
    int n3 = t * 16 + l15;
    int k0 = ks * 32 + g * 8;
    f16x8 v;
    #pragma unroll
    for (int j = 0; j < 8; ++j)
      v[j] = (f16)Wqkv[(size_t)(k0 + j) * (3 * kC) + n3];
    *reinterpret_cast<f16x8*>(wq_pack + (size_t)i * 8) = v;
  } else if (i < kWqPackChunks + kWpPackChunks) {
    int p = i - kWqPackChunks;
    int lane = p & 63;
    int chunk = p >> 6;
    int ks = chunk % 12;
    int t = chunk / 12;
    int l15 = lane & 15, g = lane >> 4;
    int n = t * 16 + l15;
    int k0 = ks * 32 + g * 8;
    f16x8 v;
    #pragma unroll
    for (int j = 0; j < 8; ++j)
      v[j] = (f16)Wproj[(size_t)(k0 + j) * kC + n];
    *reinterpret_cast<f16x8*>(wp_pack + (size_t)p * 8) = v;
  }
}

// K1: qkv = xw @ Wqkv + b. 256x128 tile, 3-buffer counted-vmcnt pipeline.
// 512 thr = 8 waves (4m x 2n), wave tile 64x64. Output packed
// [b*64+win][h*3+sec][...2048]: q,k as [tok][d]; v as [d][tok].
__global__ __launch_bounds__(512, 4) void qkv_gemm6(
    const f16* __restrict__ xw, const float* __restrict__ b_qkv,
    const f16* __restrict__ wq_pack, f16* __restrict__ qkv_ws) {
  // 3 bufs x (A 16KB + B 8KB) = 72 KB; epilogue reuses first 64 KB.
  __shared__ alignas(1024) char smem[73728];

  const int tid = threadIdx.x;
  const int wid = tid >> 6;  // 0..7
  const int lane = tid & 63;
  const int g = lane >> 4;
  const int l15 = lane & 15;
  const int wm = wid >> 1;  // 0..3: 64-row window
  const int wn = wid & 1;   // 0..1: 64-col half

  // XCD swizzle: 2304 = 8*288; n-major within XCD -> A-panel L2 reuse.
  int bid = blockIdx.x;
  int wg = (bid & 7) * 288 + (bid >> 3);
  int m_grp = wg / 9;  // [0,256): 256-row panel = 4 windows
  int n_grp = wg - m_grp * 9;
  const int mb0 = m_grp * 16;  // 16-row frag chunks
  const int nb0 = n_grp * 8;

  // stage: A chunks wid, wid+8; B chunk wid. 3 x global_load_lds(16B).
  #define STAGE(KS, BUF)                                                       \
    do {                                                                       \
      const f16* ga0 =                                                         \
          xw + (((size_t)(mb0 + wid) * 12 + (KS)) * 64 + lane) * 8;            \
      const f16* ga1 =                                                         \
          xw + (((size_t)(mb0 + 8 + wid) * 12 + (KS)) * 64 + lane) * 8;        \
      const f16* gb0 =                                                         \
          wq_pack + (((size_t)(nb0 + wid) * 12 + (KS)) * 64 + lane) * 8;       \
      char* la = smem + (BUF) * 24576 + wid * 1024;                            \
      char* lb = smem + (BUF) * 24576 + 16384 + wid * 1024;                    \
      GLOAD_LDS16(ga0, la);                                                    \
      GLOAD_LDS16(ga1, la + 8192);                                             \
      GLOAD_LDS16(gb0, lb);                                                    \
    } while (0)

  f32x4 acc[4][4];
  #pragma unroll
  for (int mt = 0; mt < 4; ++mt)
    #pragma unroll
    for (int nt = 0; nt < 4; ++nt) acc[mt][nt] = {0.f, 0.f, 0.f, 0.f};

  STAGE(0, 0);
  STAGE(1, 1);
  STAGE(2, 2);
  WAITVM(6);  // stage0 done (2 stages x 3 loads outstanding)
  __builtin_amdgcn_sched_barrier(0);
  __builtin_amdgcn_s_barrier();

  #define KITER(T, ENDVM)                                                      \
    do {                                                                       \
      constexpr int buf = (T) % 3;                                             \
      f16x8 af[4], bf[4];                                                      \
      _Pragma("unroll") for (int mt = 0; mt < 4; ++mt) af[mt] =                \
          *reinterpret_cast<const f16x8*>(smem + buf * 24576 +                 \
                                          (wm * 4 + mt) * 1024 + lane * 16);   \
      _Pragma("unroll") for (int nt = 0; nt < 4; ++nt) bf[nt] =                \
          *reinterpret_cast<const f16x8*>(smem + buf * 24576 + 16384 +         \
                                          (wn * 4 + nt) * 1024 + lane * 16);   \
      asm volatile("s_waitcnt lgkmcnt(0)" ::: "memory");                       \
      __builtin_amdgcn_sched_barrier(0);                                       \
      __builtin_amdgcn_s_barrier();                                            \
      if ((T) < 9) {                                                           \
        STAGE((T) + 3, buf);                                                   \
      }                                                                        \
      __builtin_amdgcn_s_setprio(1);                                           \
      _Pragma("unroll") for (int mt = 0; mt < 4; ++mt)                         \
          _Pragma("unroll") for (int nt = 0; nt < 4; ++nt) acc[mt][nt] =       \
          MFMA_F16(af[mt], bf[nt], acc[mt][nt]);                               \
      __builtin_amdgcn_s_setprio(0);                                           \
      WAITVM(ENDVM);                                                           \
      __builtin_amdgcn_sched_barrier(0);                                       \
      __builtin_amdgcn_s_barrier();                                            \
    } while (0)

  KITER(0, 6);
  KITER(1, 6);
  KITER(2, 6);
  KITER(3, 6);
  KITER(4, 6);
  KITER(5, 6);
  KITER(6, 6);
  KITER(7, 6);
  KITER(8, 6);
  KITER(9, 3);
  KITER(10, 0);
  KITER(11, 0);
  #undef KITER
  #undef STAGE

  // ---- epilogue: bias, LDS re-order (v transposed+swizzled), stores ----
  // eo: [win_loc(4)][hsec_loc(4)][2048] = 64 KB
  f16* eo = (f16*)smem;
  #pragma unroll
  for (int nt = 0; nt < 4; ++nt) {
    int col128 = wn * 64 + nt * 16 + l15;
    float bias = b_qkv[n_grp * 128 + col128];
    int hsec_loc = wn * 2 + (nt >> 1);  // wave-uniform
    int d = col128 & 31;
    int sec = (n_grp * 4 + hsec_loc) / 12;
    int base = (wm * 4 + hsec_loc) * 2048;
    #pragma unroll
    for (int mt = 0; mt < 4; ++mt) {
      #pragma unroll
      for (int j = 0; j < 4; ++j) {
        int tok = mt * 16 + g * 4 + j;
        f16 hv = (f16)(acc[mt][nt][j] + bias);
        if (sec == 2)
          eo[base + d * 64 + (tok ^ ((d & 7) << 3))] = hv;  // [d][tok] swz
        else
          eo[base + tok * 32 + d] = hv;                      // [tok][d]
      }
    }
  }
  __syncthreads();
  // copy out: 4096 x 16B units over 512 threads
  #pragma unroll
  for (int i = 0; i < 8; ++i) {
    int u = tid + i * 512;
    int win_loc = u >> 10;       // 0..3
    int cbl = (u >> 8) & 3;
    int inner = u & 255;
    int cb = n_grp * 4 + cbl;
    int h = cb % 12;
    int sec = cb / 12;
    size_t dst = ((size_t)(m_grp * 4 + win_loc) * 36 + h * 3 + sec) * 2048 +
                 (size_t)inner * 8;
    f16x8 hv;
    if (sec == 2) {
      int d = inner >> 3;
      int t0 = inner & 7;
      hv = *reinterpret_cast<const f16x8*>(eo + (win_loc * 4 + cbl) * 2048 +
                                           d * 64 + ((t0 * 8) ^ ((d & 7) << 3)));
    } else {
      hv = *reinterpret_cast<const f16x8*>(eo + (size_t)u * 8);
    }
    *reinterpret_cast<f16x8*>(qkv_ws + dst) = hv;
  }
}

// ---- K2 helpers (proven in R7/R8/R10/R12/R13) ----
__device__ __forceinline__ void load_qkv(const f16* __restrict__ hb,
                                         f16x8 (&qf)[4], f16x8 (&kf)[4],
                                         f16x8 (&vf)[2][2], int g, int l15) {
  #pragma unroll
  for (int mt = 0; mt < 4; ++mt)
    qf[mt] = *reinterpret_cast<const f16x8*>(hb + (mt * 16 + l15) * 32 + g * 8);
  #pragma unroll
  for (int nt = 0; nt < 4; ++nt)
    kf[nt] = *reinterpret_cast<const f16x8*>(hb + 2048 + (nt * 16 + l15) * 32 +
                                             g * 8);
  #pragma unroll
  for (int nd = 0; nd < 2; ++nd)
    #pragma unroll
    for (int ks = 0; ks < 2; ++ks)
      vf[nd][ks] = *reinterpret_cast<const f16x8*>(
          hb + 4096 + (nd * 16 + l15) * 64 + ks * 32 + g * 8);
}

__device__ __forceinline__ void attn_one(const f16x8 (&qf)[4],
                                         const f16x8 (&kf)[4],
                                         const f16x8 (&vf)[2][2],
                                         f16 (&ao)[64][392], f16 (&ps)[16][68],
                                         int wid, int g, int l15) {
  const f32x4 zero4 = {0.f, 0.f, 0.f, 0.f};
  #pragma unroll
  for (int mt = 0; mt < 4; ++mt) {
    f32x4 sw0 = MFMA_F16(kf[0], qf[mt], zero4);
    f32x4 sw1 = MFMA_F16(kf[1], qf[mt], zero4);
    f32x4 sw2 = MFMA_F16(kf[2], qf[mt], zero4);
    f32x4 sw3 = MFMA_F16(kf[3], qf[mt], zero4);
    float p[16];
    #pragma unroll
    for (int j = 0; j < 4; ++j) {
      p[j] = sw0[j] * kScale;
      p[4 + j] = sw1[j] * kScale;
      p[8 + j] = sw2[j] * kScale;
      p[12 + j] = sw3[j] * kScale;
    }
    float m0 = fmaxf(fmaxf(p[0], p[1]), fmaxf(p[2], p[3]));
    float m1 = fmaxf(fmaxf(p[4], p[5]), fmaxf(p[6], p[7]));
    float m2 = fmaxf(fmaxf(p[8], p[9]), fmaxf(p[10], p[11]));
    float m3 = fmaxf(fmaxf(p[12], p[13]), fmaxf(p[14], p[15]));
    float mx = fmaxf(fmaxf(m0, m1), fmaxf(m2, m3));
    mx = fmaxf(mx, __shfl_xor(mx, 16));
    mx = fmaxf(mx, __shfl_xor(mx, 32));
    #pragma unroll
    for (int i = 0; i < 16; ++i) p[i] = __expf(p[i] - mx);
    float s01 = (p[0] + p[1]) + (p[2] + p[3]);
    float s23 = (p[4] + p[5]) + (p[6] + p[7]);
    float s45 = (p[8] + p[9]) + (p[10] + p[11]);
    float s67 = (p[12] + p[13]) + (p[14] + p[15]);
    float s = (s01 + s23) + (s45 + s67);
    s += __shfl_xor(s, 16);
    s += __shfl_xor(s, 32);
    float inv = __builtin_amdgcn_rcpf(s);
    #pragma unroll
    for (int nt = 0; nt < 4; ++nt) {
      f16x4 h = {(f16)(p[nt * 4] * inv), (f16)(p[nt * 4 + 1] * inv),
                 (f16)(p[nt * 4 + 2] * inv), (f16)(p[nt * 4 + 3] * inv)};
      *reinterpret_cast<f16x4*>(&ps[l15][nt * 16 + g * 4]) = h;
    }
    f32x4 o0 = zero4, o1 = zero4;
    #pragma unroll
    for (int ks = 0; ks < 2; ++ks) {
      f16x8 pa = *reinterpret_cast<const f16x8*>(&ps[l15][ks * 32 + g * 8]);
      o0 = MFMA_F16(pa, vf[0][ks], o0);
      o1 = MFMA_F16(pa, vf[1][ks], o1);
    }
    #pragma unroll
    for (int j = 0; j < 4; ++j) {
      ao[mt * 16 + g * 4 + j][wid * 32 + l15] = (f16)o0[j];
      ao[mt * 16 + g * 4 + j][wid * 32 + 16 + l15] = (f16)o1[j];
    }
  }
}

__device__ __forceinline__ void proj_store(const f16 (&ao)[64][392],
                                           const f16* __restrict__ wp_pack,
                                           float* __restrict__ out, int b,
                                           int win, int wid, int g, int l15,
                                           int lane) {
  const f32x4 zero4 = {0.f, 0.f, 0.f, 0.f};
  const int wh = win >> 3, ww = win & 7;
  f32x4 pacc[4][2];
  #pragma unroll
  for (int mt = 0; mt < 4; ++mt) {
    pacc[mt][0] = zero4;
    pacc[mt][1] = zero4;
  }
  const f16* pp0 = wp_pack + ((size_t)((wid * 2) * 12) * 64 + lane) * 8;
  const f16* pp1 = wp_pack + ((size_t)((wid * 2 + 1) * 12) * 64 + lane) * 8;
  f16x8 pb0[2], pb1[2];
  pb0[0] = *reinterpret_cast<const f16x8*>(pp0);
  pb1[0] = *reinterpret_cast<const f16x8*>(pp1);
  #pragma unroll
  for (int ks = 0; ks < 12; ++ks) {
    const int cur = ks & 1;
    if (ks < 11) {
      pb0[cur ^ 1] = *reinterpret_cast<const f16x8*>(pp0 + (ks + 1) * 512);
      pb1[cur ^ 1] = *reinterpret_cast<const f16x8*>(pp1 + (ks + 1) * 512);
    }
    f16x8 paf[4];
    #pragma unroll
    for (int mt = 0; mt < 4; ++mt)
      paf[mt] = *reinterpret_cast<const f16x8*>(
          &ao[mt * 16 + l15][ks * 32 + g * 8]);
    #pragma unroll
    for (int mt = 0; mt < 4; ++mt) {
      pacc[mt][0] = MFMA_F16(paf[mt], pb0[cur], pacc[mt][0]);
      pacc[mt][1] = MFMA_F16(paf[mt], pb1[cur], pacc[mt][1]);
    }
  }
  const size_t outbase = (size_t)b * kNTok * kC;
  #pragma unroll
  for (int mt = 0; mt < 4; ++mt) {
    #pragma unroll
    for (int j = 0; j < 4; ++j) {
      int rr = mt * 16 + g * 4 + j;
      int n = (wh * 8 + (rr >> 3)) * 64 + ww * 8 + (rr & 7);
      float* orow = out + outbase + (size_t)n * kC + wid * 32;
      orow[l15] = pacc[mt][0][j];
      orow[16 + l15] = pacc[mt][1][j];
    }
  }
}

// K2: 12 waves = 12 heads; 2 windows per block with register prefetch.
__global__ __launch_bounds__(768, 3) void attn_proj3(
    const f16* __restrict__ qkv_ws, const f16* __restrict__ wp_pack,
    float* __restrict__ out) {
  __shared__ alignas(16) f16 ao[64][392];
  __shared__ alignas(16) f16 p_s[12][16][68];

  const int tid = threadIdx.x;
  const int wid = tid >> 6;  // head
  const int lane = tid & 63;
  const int g = lane >> 4;
  const int l15 = lane & 15;

  int bid = (int)blockIdx.x;             // 512 blocks
  int w2 = (bid & 7) * 64 + (bid >> 3);  // XCD swizzle
  const int b = w2 >> 5;
  const int win0 = (w2 & 31) * 2;
  const int win1 = win0 + 1;

  const f16* hb0 = qkv_ws + ((size_t)(b * 64 + win0) * 36 + wid * 3) * 2048;
  const f16* hb1 = hb0 + 36 * 2048;

  f16x8 qA[4], kA[4], vA[2][2], qB[4], kB[4], vB[2][2];
  load_qkv(hb0, qA, kA, vA, g, l15);
  __builtin_amdgcn_sched_barrier(0);
  attn_one(qA, kA, vA, ao, p_s[wid], wid, g, l15);
  load_qkv(hb1, qB, kB, vB, g, l15);  // prefetch window 1 during proj 0
  __builtin_amdgcn_sched_barrier(0);
  __syncthreads();
  proj_store(ao, wp_pack, out, b, win0, wid, g, l15, lane);
  __syncthreads();  // proj0 done reading ao before window-1 PV overwrites
  attn_one(qB, kB, vB, ao, p_s[wid], wid, g, l15);
  __syncthreads();
  proj_store(ao, wp_pack, out, b, win1, wid, g, l15, lane);
}

// ===================== fallback path (round-3 fused kernel) =====================

__global__ void prep_weights_fb(const float* __restrict__ Wqkv,
                                const float* __restrict__ Wproj,
                                f16* __restrict__ wq_pack,
                                f16* __restrict__ wp_pack) {
  int i = blockIdx.x * 256 + threadIdx.x;
  if (i < kQkvPackChunksFb) {
    int lane = i & 63;
    int chunk = i >> 6;
    int ks = chunk % 12;
    int t = (chunk / 12) % 12;
    int hp = chunk / 144;
    int l15 = lane & 15, g = lane >> 4;
    int base = t * 16;
    int hh = base / 96;
    int cc = base - hh * 96;
    int sec = cc >> 5;
    int dbhi = cc & 31;
    int n3 = sec * kC + (2 * hp + hh) * 32 + dbhi + l15;
    int k0 = ks * 32 + g * 8;
    f16x8 v;
    #pragma unroll
    for (int j = 0; j < 8; ++j)
      v[j] = (f16)Wqkv[(size_t)(k0 + j) * (3 * kC) + n3];
    *reinterpret_cast<f16x8*>(wq_pack + (size_t)i * 8) = v;
  } else if (i < kQkvPackChunksFb + kWpPackChunks) {
    int p = i - kQkvPackChunksFb;
    int lane = p & 63;
    int chunk = p >> 6;
    int ks = chunk % 12;
    int t = chunk / 12;
    int l15 = lane & 15, g = lane >> 4;
    int n = t * 16 + l15;
    int k0 = ks * 32 + g * 8;
    f16x8 v;
    #pragma unroll
    for (int j = 0; j < 8; ++j)
      v[j] = (f16)Wproj[(size_t)(k0 + j) * kC + n];
    *reinterpret_cast<f16x8*>(wp_pack + (size_t)p * 8) = v;
  }
}

__global__ __launch_bounds__(512, 2) void win_attn_fused_fb(
    const float* __restrict__ x, const float* __restrict__ b_qkv,
    const f16* __restrict__ wq_pack, const f16* __restrict__ wp_pack,
    float* __restrict__ out) {
  __shared__ alignas(16) f16 xs[64][392];
  __shared__ alignas(16) f16 ao[64][392];
  __shared__ alignas(16) f16 q_s[2][64][40];
  __shared__ alignas(16) f16 k_s[2][64][40];
  __shared__ alignas(16) f16 vT[2][32][72];
  __shared__ alignas(16) f16 p_s[8][16][72];

  const int tid = threadIdx.x;
  const int wid = tid >> 6;
  const int lane = tid & 63;
  const int g = lane >> 4;
  const int l15 = lane & 15;
  const int wm = wid >> 2;
  const int wn = wid & 3;

  const int blk = blockIdx.x;
  const int b = blk >> 6;
  const int win = blk & 63;
  const int wh = win >> 3;
  const int ww = win & 7;

  const f32x4 zero4 = {0.f, 0.f, 0.f, 0.f};

  {
    const float* xb = x + (size_t)b * kNTok * kC;
    #pragma unroll
    for (int it = 0; it < 12; ++it) {
      int idx = tid + it * 512;
      int r = idx / 96;
      int c4 = idx - r * 96;
      int n = (wh * 8 + (r >> 3)) * 64 + ww * 8 + (r & 7);
      float4 v = *reinterpret_cast<const float4*>(xb + (size_t)n * kC + c4 * 4);
      f16x4 hv = {(f16)v.x, (f16)v.y, (f16)v.z, (f16)v.w};
      *reinterpret_cast<f16x4*>(&xs[r][c4 * 4]) = hv;
    }
  }
  __syncthreads();

  for (int hp = 0; hp < 6; ++hp) {
    f32x4 acc[2][3];
    #pragma unroll
    for (int mt = 0; mt < 2; ++mt)
      #pragma unroll
      for (int nt = 0; nt < 3; ++nt) acc[mt][nt] = zero4;

    const f16* bptr[3];
    int secv[3], dbv[3], hhv[3];
    #pragma unroll
    for (int nt = 0; nt < 3; ++nt) {
      int t = wn * 3 + nt;
      int base = t * 16;
      int hh = base / 96;
      int cc = base - hh * 96;
      hhv[nt] = hh;
      secv[nt] = cc >> 5;
      dbv[nt] = cc & 31;
      bptr[nt] = wq_pack + ((size_t)((hp * 12 + t) * 12) * 64 + lane) * 8;
    }

    f16x8 bf[4][3];
    f16x8 af[2][2];
    #pragma unroll
    for (int p = 0; p < 3; ++p)
      #pragma unroll
      for (int nt = 0; nt < 3; ++nt)
        bf[p][nt] = *reinterpret_cast<const f16x8*>(bptr[nt] + p * 512);
    #pragma unroll
    for (int mt = 0; mt < 2; ++mt)
      af[0][mt] = *reinterpret_cast<const f16x8*>(
          &xs[wm * 32 + mt * 16 + l15][g * 8]);

    #pragma unroll
    for (int ks = 0; ks < 12; ++ks) {
      const int cur = ks & 3;
      const int ca = ks & 1;
      if (ks < 9) {
        const int nx = (ks + 3) & 3;
        #pragma unroll
        for (int nt = 0; nt < 3; ++nt)
          bf[nx][nt] =
              *reinterpret_cast<const f16x8*>(bptr[nt] + (ks + 3) * 512);
      }
      if (ks < 11) {
        #pragma unroll
        for (int mt = 0; mt < 2; ++mt)
          af[ca ^ 1][mt] = *reinterpret_cast<const f16x8*>(
              &xs[wm * 32 + mt * 16 + l15][(ks + 1) * 32 + g * 8]);
      }
      #pragma unroll
      for (int mt = 0; mt < 2; ++mt)
        #pragma unroll
        for (int nt = 0; nt < 3; ++nt)
          acc[mt][nt] = MFMA_F16(af[ca][mt], bf[cur][nt], acc[mt][nt]);
    }

    #pragma unroll
    for (int nt = 0; nt < 3; ++nt) {
      int hh = hhv[nt], sec = secv[nt];
      int col = dbv[nt] + l15;
      float bias = b_qkv[sec * kC + (2 * hp + hh) * 32 + col];
      #pragma unroll
      for (int mt = 0; mt < 2; ++mt) {
        #pragma unroll
        for (int j = 0; j < 4; ++j) {
          int r = wm * 32 + mt * 16 + g * 4 + j;
          f16 hv = (f16)(acc[mt][nt][j] + bias);
          if (sec == 0) q_s[hh][r][col] = hv;
          else if (sec == 1) k_s[hh][r][col] = hv;
          else vT[hh][col][r] = hv;
        }
      }
    }
    __syncthreads();

    f32x4 sacc[4];
    #pragma unroll
    for (int nt = 0; nt < 4; ++nt) sacc[nt] = zero4;
    f16x8 qa = *reinterpret_cast<const f16x8*>(&q_s[wm][wn * 16 + l15][g * 8]);
    #pragma unroll
    for (int nt = 0; nt < 4; ++nt) {
      f16x8 kb =
          *reinterpret_cast<const f16x8*>(&k_s[wm][nt * 16 + l15][g * 8]);
      sacc[nt] = MFMA_F16(qa, kb, sacc[nt]);
    }

    float pv[4][4];
    #pragma unroll
    for (int j = 0; j < 4; ++j) {
      float m = -1e30f;
      #pragma unroll
      for (int nt = 0; nt < 4; ++nt) {
        pv[nt][j] = sacc[nt][j] * kScale;
        m = fmaxf(m, pv[nt][j]);
      }
      m = fmaxf(m, __shfl_xor(m, 1));
      m = fmaxf(m, __shfl_xor(m, 2));
      m = fmaxf(m, __shfl_xor(m, 4));
      m = fmaxf(m, __shfl_xor(m, 8));
      float s = 0.f;
      #pragma unroll
      for (int nt = 0; nt < 4; ++nt) {
        pv[nt][j] = __expf(pv[nt][j] - m);
        s += pv[nt][j];
      }
      s += __shfl_xor(s, 1);
      s += __shfl_xor(s, 2);
      s += __shfl_xor(s, 4);
      s += __shfl_xor(s, 8);
      float inv = 1.0f / s;
      #pragma unroll
      for (int nt = 0; nt < 4; ++nt)
        p_s[wid][g * 4 + j][nt * 16 + l15] = (f16)(pv[nt][j] * inv);
    }

    f32x4 oacc[2];
    oacc[0] = zero4;
    oacc[1] = zero4;
    #pragma unroll
    for (int ks = 0; ks < 2; ++ks) {
      f16x8 pa =
          *reinterpret_cast<const f16x8*>(&p_s[wid][l15][ks * 32 + g * 8]);
      #pragma unroll
      for (int nt = 0; nt < 2; ++nt) {
        f16x8 vb = *reinterpret_cast<const f16x8*>(
            &vT[wm][nt * 16 + l15][ks * 32 + g * 8]);
        oacc[nt] = MFMA_F16(pa, vb, oacc[nt]);
      }
    }
    #pragma unroll
    for (int nt = 0; nt < 2; ++nt)
      #pragma unroll
      for (int j = 0; j < 4; ++j)
        ao[wn * 16 + g * 4 + j][(2 * hp + wm) * 32 + nt * 16 + l15] =
            (f16)oacc[nt][j];
    __syncthreads();
  }

  f32x4 pacc[2][6];
  #pragma unroll
  for (int mt = 0; mt < 2; ++mt)
    #pragma unroll
    for (int nt = 0; nt < 6; ++nt) pacc[mt][nt] = zero4;

  const f16* pptr[6];
  #pragma unroll
  for (int nt = 0; nt < 6; ++nt) {
    int t = wn * 6 + nt;
    pptr[nt] = wp_pack + ((size_t)(t * 12) * 64 + lane) * 8;
  }
  f16x8 pbf[3][6];
  f16x8 paf[2][2];
  #pragma unroll
  for (int p = 0; p < 2; ++p)
    #pragma unroll
    for (int nt = 0; nt < 6; ++nt)
      pbf[p][nt] = *reinterpret_cast<const f16x8*>(pptr[nt] + p * 512);
  #pragma unroll
  for (int mt = 0; mt < 2; ++mt)
    paf[0][mt] =
        *reinterpret_cast<const f16x8*>(&ao[wm * 32 + mt * 16 + l15][g * 8]);

  #pragma unroll
  for (int ks = 0; ks < 12; ++ks) {
    const int cur = ks % 3;
    const int ca = ks & 1;
    if (ks < 10) {
      const int nx = (ks + 2) % 3;
      #pragma unroll
      for (int nt = 0; nt < 6; ++nt)
        pbf[nx][nt] =
            *reinterpret_cast<const f16x8*>(pptr[nt] + (ks + 2) * 512);
    }
    if (ks < 11) {
      #pragma unroll
      for (int mt = 0; mt < 2; ++mt)
        paf[ca ^ 1][mt] = *reinterpret_cast<const f16x8*>(
            &ao[wm * 32 + mt * 16 + l15][(ks + 1) * 32 + g * 8]);
    }
    #pragma unroll
    for (int mt = 0; mt < 2; ++mt)
      #pragma unroll
      for (int nt = 0; nt < 6; ++nt)
        pacc[mt][nt] = MFMA_F16(paf[ca][mt], pbf[cur][nt], pacc[mt][nt]);
  }

  const size_t outbase = (size_t)b * kNTok * kC;
  #pragma unroll
  for (int mt = 0; mt < 2; ++mt) {
    #pragma unroll
    for (int j = 0; j < 4; ++j) {
      int r = wm * 32 + mt * 16 + g * 4 + j;
      int n = (wh * 8 + (r >> 3)) * 64 + ww * 8 + (r & 7);
      float* orow = out + outbase + (size_t)n * kC + wn * 96;
      #pragma unroll
      for (int nt = 0; nt < 6; ++nt) orow[nt * 16 + l15] = pacc[mt][nt][j];
    }
  }
}

// ===================== launch =====================

extern "C" void kernel_launch(void* const* d_in, const int* in_sizes, int n_in,
                              void* d_out, int out_size, void* d_ws,
                              size_t ws_size, hipStream_t stream) {
  const float* x = (const float*)d_in[0];
  const float* Wqkv = (const float*)d_in[1];
  const float* bqkv = (const float*)d_in[2];
  const float* Wproj = (const float*)d_in[3];
  float* out = (float*)d_out;

  if (ws_size >= kWsNeed) {
    f16* wq_pack = (f16*)d_ws;
    f16* wp_pack = (f16*)((char*)d_ws + kWqPackBytes);
    f16* qkv_ws = (f16*)((char*)d_ws + kWqPackBytes + kWpPackBytes);
    f16* xw = (f16*)d_out;  // 50 MB scratch inside the 100 MB output buffer

    int prep_blocks =
        kPrepXBlocks + (kWqPackChunks + kWpPackChunks + 255) / 256;  // 12576
    hipLaunchKernelGGL(prep_all, dim3(prep_blocks), dim3(256), 0, stream, x,
                       Wqkv, Wproj, xw, wq_pack, wp_pack);
    hipLaunchKernelGGL(qkv_gemm6, dim3(2304), dim3(512), 0, stream, xw, bqkv,
                       wq_pack, qkv_ws);
    hipLaunchKernelGGL(attn_proj3, dim3(512), dim3(768), 0, stream, qkv_ws,
                       wp_pack, out);
  } else {
    f16* wq_pack = (f16*)d_ws;
    f16* wp_pack = (f16*)((char*)d_ws + (size_t)kQkvPackChunksFb * 16);
    int prep_threads = kQkvPackChunksFb + kWpPackChunks;
    hipLaunchKernelGGL(prep_weights_fb, dim3((prep_threads + 255) / 256),
                       dim3(256), 0, stream, Wqkv, Wproj, wq_pack, wp_pack);
    hipLaunchKernelGGL(win_attn_fused_fb, dim3(16 * 64), dim3(512), 0, stream,
                       x, bqkv, wq_pack, wp_pack, out);
  }
}